// Round 8
// baseline (1121.982 us; speedup 1.0000x reference)
//
#include <hip/hip_runtime.h>
#include <hip/hip_fp16.h>

#define BATCH 65536
#define DIM   256
#define CODES 1024
#define TAU   0.20f

typedef _Float16 f16x8 __attribute__((ext_vector_type(8)));
typedef float    f32x4 __attribute__((ext_vector_type(4)));

// async global->LDS, 16B per lane; LDS dest = uniform base + lane*16
#define GLL(gptr, lptr) \
    __builtin_amdgcn_global_load_lds( \
        (const __attribute__((address_space(1))) void*)(gptr), \
        (__attribute__((address_space(3))) void*)(lptr), 16, 0, 0)

// ---------------------------------------------------------------------------
// Prep: E -> fp16 + exact |e|^2 per code (f32)
// ---------------------------------------------------------------------------
__global__ void vq_prep(const float* __restrict__ E, float* __restrict__ enorm,
                        unsigned short* __restrict__ Eh) {
    int k = blockIdx.x;      // code
    int lane = threadIdx.x;  // 0..63
    const float4 v = *(const float4*)(E + (size_t)k * DIM + lane * 4);
    float s = v.x * v.x + v.y * v.y + v.z * v.z + v.w * v.w;
    ushort4 hv;
    hv.x = __half_as_ushort(__float2half(v.x));
    hv.y = __half_as_ushort(__float2half(v.y));
    hv.z = __half_as_ushort(__float2half(v.z));
    hv.w = __half_as_ushort(__float2half(v.w));
    *(ushort4*)(Eh + (size_t)k * DIM + lane * 4) = hv;
    s += __shfl_down(s, 32);
    s += __shfl_down(s, 16);
    s += __shfl_down(s, 8);
    s += __shfl_down(s, 4);
    s += __shfl_down(s, 2);
    s += __shfl_down(s, 1);
    if (lane == 0) enorm[k] = s;
}

// ---------------------------------------------------------------------------
// Partial argmin, STATIONARY-B: one block owns (row-block of 512 rows) x
// (code-subset of 256). The 256-code fp16 panel (128 KB) is loaded to LDS
// ONCE (single __syncthreads in the kernel); then 8 independent waves sweep
// their 64 rows x 256 codes with no further synchronization. Emits
// (best, sec, idx) per (row, subset).
//   Structural contrast with R5/R7: zero per-tile barriers (R5/R7 paid
//   ~1150 cyc/block-tile x 64 tiles on a synced staging loop).
//   XCD swizzle: the 4 subset-blocks of one row-block land on one XCD so
//   their X reads dedup in that XCD's L2.
// ---------------------------------------------------------------------------
__global__ __launch_bounds__(512, 2) void vq_partial(
    const float* __restrict__ X,
    const unsigned short* __restrict__ Eh,
    const float* __restrict__ enorm,
    float2* __restrict__ bs, int* __restrict__ pid) {

    __shared__ unsigned short Eb[16][8][512];   // 16 panels x 8 ksteps = 128 KB

    const int tid  = threadIdx.x;
    const int lane = tid & 63;
    const int w    = tid >> 6;               // wave 0..7
    const int m    = lane & 15;              // A row-in-16 / C code col
    const int quad = lane >> 4;              // 0..3
    // bid -> (rb, sub): 4 sub-blocks of one rb share an XCD (bid%8 = XCD)
    const int bid = blockIdx.x;
    const int rb  = (bid & 7) + 8 * (bid >> 5);   // 0..127
    const int sub = (bid >> 3) & 3;               // 0..3
    const int c0  = sub * 256;
    const int wrow = rb * 512 + w * 64;           // this wave's first row

    // ---- stage the code panel ONCE: wave w loads panels 2w, 2w+1 ----
    #pragma unroll
    for (int pp = 0; pp < 2; ++pp) {
        const int p = 2 * w + pp;
        const size_t rbase = (size_t)(c0 + p * 16 + m) * DIM + quad * 8;
        #pragma unroll
        for (int s = 0; s < 8; ++s)
            GLL(Eh + rbase + s * 32, &Eb[p][s][0]);
    }
    __syncthreads();   // the only barrier: drains all GLLs

    // ---- sweep rows in 2 chunks of 32 (2 row-groups x 8 ksteps A-frags) ----
    #pragma unroll 1
    for (int ch = 0; ch < 2; ++ch) {
        const int chrow = wrow + ch * 32;
        f16x8 ah[2][8];
        #pragma unroll
        for (int g = 0; g < 2; ++g) {
            const float* xr = X + (size_t)(chrow + g * 16 + m) * DIM + quad * 8;
            #pragma unroll
            for (int s = 0; s < 8; ++s) {
                float4 p0 = *(const float4*)(xr + s * 32);
                float4 p1 = *(const float4*)(xr + s * 32 + 4);
                ah[g][s][0] = (_Float16)p0.x; ah[g][s][1] = (_Float16)p0.y;
                ah[g][s][2] = (_Float16)p0.z; ah[g][s][3] = (_Float16)p0.w;
                ah[g][s][4] = (_Float16)p1.x; ah[g][s][5] = (_Float16)p1.y;
                ah[g][s][6] = (_Float16)p1.z; ah[g][s][7] = (_Float16)p1.w;
            }
        }

        float best[2][4], sec[2][4];
        int   bidx[2][4];
        #pragma unroll
        for (int g = 0; g < 2; ++g)
            #pragma unroll
            for (int r = 0; r < 4; ++r) {
                best[g][r] = 3.4e38f; sec[g][r] = 3.4e38f; bidx[g][r] = 0;
            }

        for (int p = 0; p < 16; ++p) {
            const int   c  = c0 + p * 16 + m;
            const float es = enorm[c];           // L1-hot after first pass
            f32x4 acc0 = {0.f, 0.f, 0.f, 0.f}, acc1 = {0.f, 0.f, 0.f, 0.f};
            const unsigned short* bp = &Eb[p][0][0];
            #pragma unroll
            for (int s = 0; s < 8; ++s) {
                f16x8 bf = *(const f16x8*)(bp + s * 512 + lane * 8);
                acc0 = __builtin_amdgcn_mfma_f32_16x16x32_f16(ah[0][s], bf, acc0, 0, 0, 0);
                acc1 = __builtin_amdgcn_mfma_f32_16x16x32_f16(ah[1][s], bf, acc1, 0, 0, 0);
            }
            // C layout: col = lane&15 (code), row = quad*4 + reg
            #pragma unroll
            for (int r = 0; r < 4; ++r) {
                float d0 = __builtin_fmaf(-2.0f, acc0[r], es);
                if (d0 < best[0][r]) { sec[0][r] = best[0][r]; best[0][r] = d0; bidx[0][r] = c; }
                else if (d0 < sec[0][r]) sec[0][r] = d0;
                float d1 = __builtin_fmaf(-2.0f, acc1[r], es);
                if (d1 < best[1][r]) { sec[1][r] = best[1][r]; best[1][r] = d1; bidx[1][r] = c; }
                else if (d1 < sec[1][r]) sec[1][r] = d1;
            }
        }

        // cross-lane argmin reduce over the 16 code-columns (low 4 lane bits)
        #pragma unroll
        for (int g = 0; g < 2; ++g) {
            #pragma unroll
            for (int r = 0; r < 4; ++r) {
                float b0 = best[g][r], s0 = sec[g][r];
                int   i0 = bidx[g][r];
                #pragma unroll
                for (int msk = 1; msk < 16; msk <<= 1) {
                    float ob = __shfl_xor(b0, msk);
                    float os = __shfl_xor(s0, msk);
                    int   oi = __shfl_xor(i0, msk);
                    if (ob < b0 || (ob == b0 && oi < i0)) {
                        s0 = fminf(b0, os);
                        b0 = ob; i0 = oi;
                    } else {
                        s0 = fminf(s0, ob);
                    }
                }
                best[g][r] = b0; sec[g][r] = s0; bidx[g][r] = i0;
            }
        }

        if (m == 0) {
            #pragma unroll
            for (int g = 0; g < 2; ++g)
                #pragma unroll
                for (int r = 0; r < 4; ++r) {
                    const int row = chrow + g * 16 + quad * 4 + r;
                    bs[row * 4 + sub]  = make_float2(best[g][r], sec[g][r]);
                    pid[row * 4 + sub] = bidx[g][r];
                }
        }
    }
}

// ---------------------------------------------------------------------------
// Finish: merge 4 subset-partials per row + block-local exact fp32 repair
// for near-ties (margin < TAU) + epilogue (loss/qst/onehot).
//   block = 256 thr (4 waves), 64 rows/block, grid = 1024.
// ---------------------------------------------------------------------------
__global__ __launch_bounds__(256) void vq_finish(
    const float* __restrict__ X, const float* __restrict__ E,
    const float* __restrict__ enorm,
    const float2* __restrict__ bs, const int* __restrict__ pid,
    float* __restrict__ loss, float* __restrict__ qst, float* __restrict__ onehot) {

    __shared__ int   ridx[64];
    __shared__ int   flags[64];
    __shared__ int   nflag;
    __shared__ float wrb[4];
    __shared__ int   wri[4];

    const int tid  = threadIdx.x;
    const int lane = tid & 63;
    const int w    = tid >> 6;
    const int row0 = blockIdx.x * 64;

    if (tid == 0) nflag = 0;
    __syncthreads();

    // ---- merge partials (1 thread per row) ----
    if (tid < 64) {
        const int row = row0 + tid;
        float best = 3.4e38f, sec = 3.4e38f;
        int   idx  = 0;
        #pragma unroll
        for (int j = 0; j < 4; ++j) {        // ascending code ranges
            const float2 v = bs[row * 4 + j];
            const int    i = pid[row * 4 + j];
            if (v.x < best || (v.x == best && i < idx)) {
                sec = fminf(sec, best);
                best = v.x; idx = i;
                sec = fminf(sec, v.y);
            } else {
                sec = fminf(sec, fminf(v.x, v.y));
            }
        }
        ridx[tid] = idx;
        if (sec - best < TAU) {              // near-tie: exact recheck
            int p = atomicAdd(&nflag, 1);
            flags[p] = tid;
        }
    }
    __syncthreads();

    // ---- block-local exact repair: 1 code/thread x 4 passes per row ----
    const int nf = nflag;
    for (int f = 0; f < nf; ++f) {
        const int lrow = flags[f];
        const int row  = __builtin_amdgcn_readfirstlane(row0 + lrow);
        const float* xr = X + (size_t)row * DIM;
        float bb = 3.4e38f; int bi = 0;
        #pragma unroll
        for (int p = 0; p < 4; ++p) {
            const int c = p * 256 + tid;
            const float* er = E + (size_t)c * DIM;
            float s = 0.f;
            #pragma unroll 4
            for (int j = 0; j < DIM; j += 4) {
                float4 ev = *(const float4*)(er + j);
                float4 xv = *(const float4*)(xr + j);
                s += xv.x * ev.x + xv.y * ev.y + xv.z * ev.z + xv.w * ev.w;
            }
            float d = enorm[c] - 2.0f * s;
            if (d < bb) { bb = d; bi = c; }   // p ascending -> lowest idx kept
        }
        #pragma unroll
        for (int msk = 1; msk < 64; msk <<= 1) {
            float ob = __shfl_xor(bb, msk);
            int   oi = __shfl_xor(bi, msk);
            if (ob < bb || (ob == bb && oi < bi)) { bb = ob; bi = oi; }
        }
        if (lane == 0) { wrb[w] = bb; wri[w] = bi; }
        __syncthreads();
        if (tid == 0) {
            float fb = wrb[0]; int fi = wri[0];
            #pragma unroll
            for (int k = 1; k < 4; ++k)
                if (wrb[k] < fb || (wrb[k] == fb && wri[k] < fi)) { fb = wrb[k]; fi = wri[k]; }
            ridx[lrow] = fi;
        }
        __syncthreads();
    }

    // ---- epilogue: wave w writes rows [row0 + w*16, +16) ----
    #pragma unroll 4
    for (int j = 0; j < 16; ++j) {
        const int lrow = w * 16 + j;
        const int idx  = ridx[lrow];
        const int row  = row0 + lrow;
        const size_t xb = (size_t)row * DIM + lane * 4;
        float4 x = *(const float4*)(X + xb);
        float4 q = *(const float4*)(E + (size_t)idx * DIM + lane * 4);
        float4 dl = {q.x - x.x, q.y - x.y, q.z - x.z, q.w - x.w};
        float4 lo = {0.25f * dl.x * dl.x, 0.25f * dl.y * dl.y,
                     0.25f * dl.z * dl.z, 0.25f * dl.w * dl.w};
        float4 qs = {x.x + dl.x, x.y + dl.y, x.z + dl.z, x.w + dl.w};
        *(float4*)(loss + xb) = lo;
        *(float4*)(qst + xb)  = qs;
        const size_t ob = (size_t)row * CODES;
        const int slot = idx >> 2, r3 = idx & 3;
        #pragma unroll
        for (int jj = 0; jj < 4; ++jj) {
            f32x4 z = {0.f, 0.f, 0.f, 0.f};
            if (slot == jj * 64 + lane) z[r3] = 1.0f;
            __builtin_nontemporal_store(z, (f32x4*)(onehot + ob + jj * 256 + lane * 4));
        }
    }
}

extern "C" void kernel_launch(void* const* d_in, const int* in_sizes, int n_in,
                              void* d_out, int out_size, void* d_ws, size_t ws_size,
                              hipStream_t stream) {
    const float* X = (const float*)d_in[0];   // (65536, 256)
    const float* E = (const float*)d_in[1];   // (1024, 256)
    float* out = (float*)d_out;
    float* loss   = out;
    float* qst    = out + (size_t)BATCH * DIM;
    float* onehot = out + (size_t)2 * BATCH * DIM;

    char* ws = (char*)d_ws;
    float*          enorm = (float*)ws;                          // 4 KB
    unsigned short* Eh    = (unsigned short*)(ws + 4096);        // 512 KB
    float2*         bs    = (float2*)(ws + 528384);              // 2 MB
    int*            pid   = (int*)(ws + 2625536);                // 1 MB

    vq_prep<<<CODES, 64, 0, stream>>>(E, enorm, Eh);
    vq_partial<<<512, 512, 0, stream>>>(X, Eh, enorm, bs, pid);
    vq_finish<<<BATCH / 64, 256, 0, stream>>>(X, E, enorm, bs, pid,
                                              loss, qst, onehot);
}

// Round 10
// 736.883 us; speedup vs baseline: 1.5226x; 1.5226x over previous
//
#include <hip/hip_runtime.h>
#include <hip/hip_fp16.h>

#define BATCH 65536
#define DIM   256
#define CODES 1024
#define TAU   0.20f

typedef _Float16 f16x8 __attribute__((ext_vector_type(8)));
typedef float    f32x4 __attribute__((ext_vector_type(4)));

// async global->LDS, 16B per lane; LDS dest = uniform base + lane*16
#define GLL(gptr, lptr) \
    __builtin_amdgcn_global_load_lds( \
        (const __attribute__((address_space(1))) void*)(gptr), \
        (__attribute__((address_space(3))) void*)(lptr), 16, 0, 0)

// ---------------------------------------------------------------------------
// Prep: E -> fp16 + exact |e|^2 per code (f32)
// ---------------------------------------------------------------------------
__global__ void vq_prep(const float* __restrict__ E, float* __restrict__ enorm,
                        unsigned short* __restrict__ Eh) {
    int k = blockIdx.x;      // code
    int lane = threadIdx.x;  // 0..63
    const float4 v = *(const float4*)(E + (size_t)k * DIM + lane * 4);
    float s = v.x * v.x + v.y * v.y + v.z * v.z + v.w * v.w;
    ushort4 hv;
    hv.x = __half_as_ushort(__float2half(v.x));
    hv.y = __half_as_ushort(__float2half(v.y));
    hv.z = __half_as_ushort(__float2half(v.z));
    hv.w = __half_as_ushort(__float2half(v.w));
    *(ushort4*)(Eh + (size_t)k * DIM + lane * 4) = hv;
    s += __shfl_down(s, 32);
    s += __shfl_down(s, 16);
    s += __shfl_down(s, 8);
    s += __shfl_down(s, 4);
    s += __shfl_down(s, 2);
    s += __shfl_down(s, 1);
    if (lane == 0) enorm[k] = s;
}

// ---------------------------------------------------------------------------
// MEGAKERNEL v3: R5 skeleton with 4-tile SUPER-ROUNDS.
//   block = 512 thr (8 waves), 128 rows/block, grid = 512 (2 blocks/CU).
//   Cross-round evidence (R1/R5/R7): cost per synchronized staging round is
//   ~fixed (~4.7 us at 512thr) regardless of per-round work -> amortize it:
//   stage 64 codes (4 tiles, 32 KB) per round, 16 rounds instead of 64.
//   Per wave per round: 4 GLLs staged, 32 ds_read_b128 + 32 MFMA + argmin,
//   ONE __syncthreads (drains prefetch for next round + protects reuse).
//   Then block-local cheap exact repair for near-ties + fused epilogue.
// ---------------------------------------------------------------------------
__global__ __launch_bounds__(512, 4) void vq_fused(
    const float* __restrict__ X,
    const unsigned short* __restrict__ Eh,
    const float* __restrict__ enorm,
    const float* __restrict__ E,
    float* __restrict__ loss, float* __restrict__ qst, float* __restrict__ onehot) {

    // per buffer: 4 tiles x (8 ksteps x 64 lanes x 8 fp16) = 32 KB
    __shared__ unsigned short Eb[2][4][4096];   // 64 KB
    __shared__ float EsL[CODES];                // 4 KB
    __shared__ int   ridx[128];                 // per-row chosen index
    __shared__ int   flags[128];                // rows needing exact repair
    __shared__ int   nflag;
    __shared__ float wrb[8];
    __shared__ int   wri[8];

    const int tid  = threadIdx.x;
    const int lane = tid & 63;
    const int w    = tid >> 6;               // wave 0..7 (stages k-slot w)
    const int m    = lane & 15;              // A row-in-16 / C code col
    const int quad = lane >> 4;              // 0..3
    const int row0 = blockIdx.x * 128;       // block base row
    const int wrow = row0 + w * 16;          // this wave's first row

    if (tid == 0) nflag = 0;

    // wave w stages its k-slot (k = w*32 + quad*8) for the 4 tiles of round R
    #define STAGE4(R, B) do { \
        _Pragma("unroll") \
        for (int tt_ = 0; tt_ < 4; ++tt_) { \
            const size_t rb_ = (size_t)(((R) * 4 + tt_) * 16 + m) * DIM + w * 32 + quad * 8; \
            GLL(Eh + rb_, &Eb[(B)][tt_][w * 512]); \
        } \
    } while (0)

    // prologue: stage round 0 into buf 0 (in flight during A-frag build)
    STAGE4(0, 0);

    for (int i = tid; i < CODES; i += 512) EsL[i] = enorm[i];

    // ---- A fragments: 16 rows, 8 ksteps fp16 (32 VGPRs) ----
    f16x8 ah[8];
    {
        const float* xr = X + (size_t)(wrow + m) * DIM + quad * 8;
        #pragma unroll
        for (int s = 0; s < 8; ++s) {
            float4 p0 = *(const float4*)(xr + s * 32);
            float4 p1 = *(const float4*)(xr + s * 32 + 4);
            ah[s][0] = (_Float16)p0.x; ah[s][1] = (_Float16)p0.y;
            ah[s][2] = (_Float16)p0.z; ah[s][3] = (_Float16)p0.w;
            ah[s][4] = (_Float16)p1.x; ah[s][5] = (_Float16)p1.y;
            ah[s][6] = (_Float16)p1.z; ah[s][7] = (_Float16)p1.w;
        }
    }

    __syncthreads();   // drains round-0 GLLs + EsL + nflag init

    float best[4], sec[4];
    int   bidx[4];
    #pragma unroll
    for (int i = 0; i < 4; ++i) { best[i] = 3.4e38f; sec[i] = 3.4e38f; bidx[i] = 0; }

    for (int rnd = 0; rnd < 16; ++rnd) {
        const int buf = rnd & 1;
        if (rnd < 15) STAGE4(rnd + 1, buf ^ 1);   // async prefetch next round

        #pragma unroll
        for (int tt = 0; tt < 4; ++tt) {
            const int t = rnd * 4 + tt;
            f32x4 accA = {0.f, 0.f, 0.f, 0.f}, accB = {0.f, 0.f, 0.f, 0.f};
            const unsigned short* b = &Eb[buf][tt][0];
            #pragma unroll
            for (int s = 0; s < 4; ++s) {
                f16x8 bh = *(const f16x8*)(b + s * 512 + lane * 8);
                accA = __builtin_amdgcn_mfma_f32_16x16x32_f16(ah[s], bh, accA, 0, 0, 0);
            }
            #pragma unroll
            for (int s = 4; s < 8; ++s) {
                f16x8 bh = *(const f16x8*)(b + s * 512 + lane * 8);
                accB = __builtin_amdgcn_mfma_f32_16x16x32_f16(ah[s], bh, accB, 0, 0, 0);
            }
            // C layout: col = lane&15 (code), row = quad*4 + reg
            const float es = EsL[t * 16 + m];
            const int   c  = t * 16 + m;
            #pragma unroll
            for (int r = 0; r < 4; ++r) {
                float d = __builtin_fmaf(-2.0f, accA[r] + accB[r], es);
                if (d < best[r]) { sec[r] = best[r]; best[r] = d; bidx[r] = c; }
                else if (d < sec[r]) sec[r] = d;
            }
        }
        __syncthreads();   // drains prefetch + protects buf^1 reuse
    }

    // cross-lane argmin reduce over the 16 code-columns (low 4 lane bits)
    #pragma unroll
    for (int i = 0; i < 4; ++i) {
        float b0 = best[i], s0 = sec[i];
        int   i0 = bidx[i];
        #pragma unroll
        for (int msk = 1; msk < 16; msk <<= 1) {
            float ob = __shfl_xor(b0, msk);
            float os = __shfl_xor(s0, msk);
            int   oi = __shfl_xor(i0, msk);
            if (ob < b0 || (ob == b0 && oi < i0)) {
                s0 = fminf(b0, os);
                b0 = ob; i0 = oi;
            } else {
                s0 = fminf(s0, ob);
            }
        }
        best[i] = b0; sec[i] = s0; bidx[i] = i0;
    }

    // publish per-row indices; flag near-ties into the block-local list
    if (m == 0) {
        #pragma unroll
        for (int r = 0; r < 4; ++r) {
            const int lrow = w * 16 + quad * 4 + r;
            ridx[lrow] = bidx[r];
            if (sec[r] - best[r] < TAU) {
                int p = atomicAdd(&nflag, 1);   // LDS atomic
                flags[p] = lrow;
            }
        }
    }
    __syncthreads();

    // ---- block-local exact repair: 2 codes/thread per row (512 thr) ----
    const int nf = nflag;
    for (int f = 0; f < nf; ++f) {
        const int lrow = flags[f];
        const int row  = __builtin_amdgcn_readfirstlane(row0 + lrow);
        const float* xr = X + (size_t)row * DIM;
        float bb = 3.4e38f; int bi = 0;
        #pragma unroll
        for (int p = 0; p < 2; ++p) {
            const int c = p * 512 + tid;
            const float* er = E + (size_t)c * DIM;
            float s = 0.f;
            #pragma unroll 4
            for (int j = 0; j < DIM; j += 4) {
                float4 ev = *(const float4*)(er + j);
                float4 xv = *(const float4*)(xr + j);
                s += xv.x * ev.x + xv.y * ev.y + xv.z * ev.z + xv.w * ev.w;
            }
            float d = enorm[c] - 2.0f * s;
            if (d < bb) { bb = d; bi = c; }   // p ascending -> lowest idx kept
        }
        // wave reduce then cross-wave merge (lexicographic (d, idx))
        #pragma unroll
        for (int msk = 1; msk < 64; msk <<= 1) {
            float ob = __shfl_xor(bb, msk);
            int   oi = __shfl_xor(bi, msk);
            if (ob < bb || (ob == bb && oi < bi)) { bb = ob; bi = oi; }
        }
        if (lane == 0) { wrb[w] = bb; wri[w] = bi; }
        __syncthreads();
        if (tid == 0) {
            float fb = wrb[0]; int fi = wri[0];
            #pragma unroll
            for (int k = 1; k < 8; ++k)
                if (wrb[k] < fb || (wrb[k] == fb && wri[k] < fi)) { fb = wrb[k]; fi = wri[k]; }
            ridx[lrow] = fi;
        }
        __syncthreads();
    }

    // ---- fused epilogue: wave w writes rows [wrow, wrow+16) ----
    #pragma unroll 4
    for (int j = 0; j < 16; ++j) {
        const int lrow = w * 16 + j;
        const int idx  = ridx[lrow];
        const int row  = row0 + lrow;
        const size_t xb = (size_t)row * DIM + lane * 4;
        float4 x = *(const float4*)(X + xb);
        float4 q = *(const float4*)(E + (size_t)idx * DIM + lane * 4);
        float4 dl = {q.x - x.x, q.y - x.y, q.z - x.z, q.w - x.w};
        float4 lo = {0.25f * dl.x * dl.x, 0.25f * dl.y * dl.y,
                     0.25f * dl.z * dl.z, 0.25f * dl.w * dl.w};
        float4 qs = {x.x + dl.x, x.y + dl.y, x.z + dl.z, x.w + dl.w};
        *(float4*)(loss + xb) = lo;
        *(float4*)(qst + xb)  = qs;
        const size_t ob = (size_t)row * CODES;
        const int slot = idx >> 2, r3 = idx & 3;
        #pragma unroll
        for (int jj = 0; jj < 4; ++jj) {
            f32x4 z = {0.f, 0.f, 0.f, 0.f};
            if (slot == jj * 64 + lane) z[r3] = 1.0f;
            __builtin_nontemporal_store(z, (f32x4*)(onehot + ob + jj * 256 + lane * 4));
        }
    }
    #undef STAGE4
}

extern "C" void kernel_launch(void* const* d_in, const int* in_sizes, int n_in,
                              void* d_out, int out_size, void* d_ws, size_t ws_size,
                              hipStream_t stream) {
    const float* X = (const float*)d_in[0];   // (65536, 256)
    const float* E = (const float*)d_in[1];   // (1024, 256)
    float* out = (float*)d_out;
    float* loss   = out;
    float* qst    = out + (size_t)BATCH * DIM;
    float* onehot = out + (size_t)2 * BATCH * DIM;

    char* ws = (char*)d_ws;
    float*          enorm  = (float*)ws;                        // 4 KB
    unsigned short* Eh     = (unsigned short*)(ws + 4096);      // 512 KB

    vq_prep<<<CODES, 64, 0, stream>>>(E, enorm, Eh);
    vq_fused<<<BATCH / 128, 512, 0, stream>>>(X, Eh, enorm, E,
                                              loss, qst, onehot);
}